// Round 5
// baseline (415.154 us; speedup 1.0000x reference)
//
#include <hip/hip_runtime.h>
#include <hip/hip_bf16.h>

// Problem constants (hardcoded from setup_inputs)
#define B_    2
#define NTOK  65536          // tokens per batch (256*256)
#define C_    256
#define H_    8
#define HD_   32
#define G_    512
#define S_    128            // tokens per cell
#define BN    (B_*NTOK)      // 131072 rows per tensor
#define M3    (3*BN)         // 393216 rows for fused qkv GEMM

typedef __attribute__((ext_vector_type(8))) short short8;   // 8 bf16 = 4 VGPRs
typedef __attribute__((ext_vector_type(4))) float f32x4;

// Native bf16 convert (RNE) — lowers to v_cvt_pk_bf16_f32 on gfx950.
__device__ __forceinline__ ushort f2bf(float f) {
  __bf16 h = (__bf16)f;
  return __builtin_bit_cast(unsigned short, h);
}
__device__ __forceinline__ unsigned pk2(float lo, float hi) {
  return (unsigned)f2bf(lo) | ((unsigned)f2bf(hi) << 16);
}

// async global->LDS, 16B per lane, wave-uniform LDS base + lane*16
__device__ __forceinline__ void gl16(const void* g, void* l) {
  __builtin_amdgcn_global_load_lds(
      (const __attribute__((address_space(1))) unsigned int*)g,
      (__attribute__((address_space(3))) unsigned int*)l, 16, 0, 0);
}

// swizzle for 4-chunk rows (32 bf16/row): slot = (c ^ r ^ (r>>2)) & 3
#define SW4(c, r) ((((c) ^ (r) ^ ((r) >> 2))) & 3)

// ---------------------------------------------------------------------------
// K0: build pre-swizzled bf16 LDS tile images of Wq and Wp.
// Image layout (per weight): [ks=K/64][256 rows][8 chunk-slots of 8 bf16],
// chunk c stored at slot c ^ (r&7)  -> global_load_lds copies it linearly.
// ---------------------------------------------------------------------------
__global__ __launch_bounds__(256) void k_prep(const float* __restrict__ Wq,
                                              const float* __restrict__ Wp,
                                              ushort* __restrict__ Wq_img,
                                              ushort* __restrict__ Wp_img) {
  int gid = blockIdx.x * 256 + threadIdx.x;     // [2][4][256][8] = 16384 tasks
  int w = gid >> 13, rem = gid & 8191;
  int ks = rem >> 11, rem2 = rem & 2047;
  int r = rem2 >> 3, c = rem2 & 7;
  const float* W = w ? Wp : Wq;
  ushort* img = w ? Wp_img : Wq_img;
  const float4* s = reinterpret_cast<const float4*>(W + (size_t)r * 256 + ks * 64 + c * 8);
  float4 a = s[0], b = s[1];
  uint4 o;
  o.x = pk2(a.x, a.y); o.y = pk2(a.z, a.w);
  o.z = pk2(b.x, b.y); o.w = pk2(b.z, b.w);
  *reinterpret_cast<uint4*>(img + ks * 16384 + r * 64 + ((c ^ (r & 7)) << 3)) = o;
}

// ---------------------------------------------------------------------------
// K1: build per-(batch,cell) token lists via atomics (order within cell is
// irrelevant: attention is permutation-invariant within a cell).
// ---------------------------------------------------------------------------
__global__ __launch_bounds__(256) void k_group(const int* __restrict__ vor,
                                               int* __restrict__ grp,
                                               int* __restrict__ cnt) {
  int idx = blockIdx.x * 256 + threadIdx.x;
  int b = idx >> 16;
  int n = idx & (NTOK - 1);
  int g = vor[idx] - 1;
  int pos = atomicAdd(&cnt[(b << 9) + g], 1);
  grp[((b << 9) + g) * S_ + pos] = n;
}

// ---------------------------------------------------------------------------
// K2: fused QKV projection: [M3,256] x Wq^T + bq -> bf16 qkv[3][BN][256]
// 128x256 (full-N) tile, BK=64, 8 waves (2x4), 16x16x32 bf16 MFMA.
// A: ALL 16 float4 loads hoisted to block start (one HBM-latency payment).
// B: global_load_lds from pre-swizzled image, double-buffered.
// Epilogue: swizzled LDS staging -> fully coalesced uint4 stores.
// ---------------------------------------------------------------------------
__global__ __launch_bounds__(512, 4) void k_proj_qkv(
    const float* __restrict__ xq, const float* __restrict__ xk,
    const float* __restrict__ xv, const ushort* __restrict__ Wq_img,
    const float* __restrict__ bq, ushort* __restrict__ qkv) {
  __shared__ ushort As[128 * 64];
  __shared__ ushort Bs[2][256 * 64];
  int mt = blockIdx.x;
  int t = mt >> 10;                             // which of xq/xk/xv
  const float* A = (t == 0) ? xq : (t == 1) ? xk : xv;
  size_t abase = (size_t)(mt & 1023) * 128 * 256;
  int row0 = mt * 128;

  int tid = threadIdx.x, lane = tid & 63, wave = tid >> 6;
  int l15 = lane & 15, hi = lane >> 4;
  int wr = (wave >> 2) * 64, wc = (wave & 3) * 64;
  int sr = tid >> 2, sq = tid & 3;              // A staging: row, quarter

  const float* aptr = A + abase + (size_t)sr * 256 + sq * 16;
  int boff = wave * 4096 + lane * 16;           // B staging byte offset

  f32x4 acc[4][4] = {};
  // deep prefetch: the thread's whole A row-slice (4 K-steps x 4 float4)
  float4 ar[4][4];
#pragma unroll
  for (int ks = 0; ks < 4; ++ks) {
    const float4* p = reinterpret_cast<const float4*>(aptr + ks * 64);
#pragma unroll
    for (int j = 0; j < 4; ++j) ar[ks][j] = p[j];
  }
#pragma unroll
  for (int j = 0; j < 4; ++j)
    gl16((const char*)Wq_img + boff + j * 1024, (char*)Bs[0] + boff + j * 1024);

#pragma unroll
  for (int ks = 0; ks < 4; ++ks) {
    uint4 w0, w1;
    w0.x = pk2(ar[ks][0].x, ar[ks][0].y); w0.y = pk2(ar[ks][0].z, ar[ks][0].w);
    w0.z = pk2(ar[ks][1].x, ar[ks][1].y); w0.w = pk2(ar[ks][1].z, ar[ks][1].w);
    w1.x = pk2(ar[ks][2].x, ar[ks][2].y); w1.y = pk2(ar[ks][2].z, ar[ks][2].w);
    w1.z = pk2(ar[ks][3].x, ar[ks][3].y); w1.w = pk2(ar[ks][3].z, ar[ks][3].w);
    *reinterpret_cast<uint4*>(&As[sr * 64 + (((sq * 2) ^ (sr & 7)) << 3)]) = w0;
    *reinterpret_cast<uint4*>(&As[sr * 64 + (((sq * 2 + 1) ^ (sr & 7)) << 3)]) = w1;
    __syncthreads();                            // A,B of step ks visible
    if (ks < 3) {
#pragma unroll
      for (int j = 0; j < 4; ++j)
        gl16((const char*)Wq_img + (ks + 1) * 32768 + boff + j * 1024,
             (char*)Bs[(ks + 1) & 1] + boff + j * 1024);
    }
    const ushort* Bcur = Bs[ks & 1];
#pragma unroll
    for (int kk = 0; kk < 2; ++kk) {
      int ck = kk * 4 + hi;
      short8 af[4], bfr[4];
#pragma unroll
      for (int m = 0; m < 4; ++m) {
        int r = wr + m * 16 + l15;
        af[m] = *reinterpret_cast<const short8*>(&As[r * 64 + ((ck ^ (r & 7)) << 3)]);
      }
#pragma unroll
      for (int n = 0; n < 4; ++n) {
        int r = wc + n * 16 + l15;
        bfr[n] = *reinterpret_cast<const short8*>(&Bcur[r * 64 + ((ck ^ (r & 7)) << 3)]);
      }
#pragma unroll
      for (int m = 0; m < 4; ++m)
#pragma unroll
        for (int n = 0; n < 4; ++n)
          acc[m][n] = __builtin_amdgcn_mfma_f32_16x16x32_bf16(af[m], bfr[n], acc[m][n], 0, 0, 0);
    }
    __syncthreads();                            // LDS free for next step
  }

  // epilogue: stage tile (bias added, bf16) into Bs, chunk-swizzled so the
  // 4 hi-groups land on disjoint bank quarters; sweep with coalesced 16B.
  ushort* Ot = (ushort*)Bs;                     // 64KB = 128 rows x 32 chunks
#pragma unroll
  for (int n = 0; n < 4; ++n) {
    int col = wc + n * 16 + l15;
    float bv = bq[col];
    int c = col >> 3, ci = col & 7;
#pragma unroll
    for (int m = 0; m < 4; ++m) {
      int r0 = wr + m * 16 + hi * 4;
#pragma unroll
      for (int j = 0; j < 4; ++j) {
        int r = r0 + j;
        int slot = c ^ (((r >> 2) & 3) << 1);
        Ot[r * 256 + slot * 8 + ci] = f2bf(acc[m][n][j] + bv);
      }
    }
  }
  __syncthreads();
  {
    size_t gbase = (size_t)row0 * 256;
#pragma unroll
    for (int s = 0; s < 8; ++s) {
      int off = s * 4096 + tid * 8;
      int r = off >> 8, cc = (off >> 3) & 31;
      int slot = cc ^ (((r >> 2) & 3) << 1);
      *reinterpret_cast<uint4*>(qkv + gbase + off) =
          *reinterpret_cast<const uint4*>(Ot + r * 256 + slot * 8);
    }
  }
}

// ---------------------------------------------------------------------------
// K3: per-(b,cell,head) attention. Qs/Ks aliased into the Ps region.
// Output scatter goes through LDS -> 16B stores (one 64B line per token).
// ---------------------------------------------------------------------------
__global__ __launch_bounds__(256) void k_attn(const ushort* __restrict__ qkv,
                                              const int* __restrict__ grp,
                                              ushort* __restrict__ attn_out) {
  __shared__ int toks[128];
  __shared__ ushort PsB[128 * 128];   // phase1: Qs=[0,4096) Ks=[4096,8192); phase2: Ps
  __shared__ ushort Vt[32 * 128];     // V transposed: [ch][tok]
  ushort* Qs = PsB;
  ushort* Ks = PsB + 4096;
  ushort* Ps = PsB;

  int bid = blockIdx.x;
  int h = bid & 7, g = (bid >> 3) & (G_ - 1), b = bid >> 12;
  int tid = threadIdx.x, lane = tid & 63, wave = tid >> 6;
  int l15 = lane & 15, hi = lane >> 4;

  if (tid < 128) toks[tid] = grp[((b << 9) + g) * S_ + tid];
  __syncthreads();

  {  // stage Q,K (row-major, swizzled) and V (transposed, swizzled)
    int r = tid >> 1;
    int cp = (tid & 1) * 2;   // this thread covers chunks cp, cp+1
    int tok = toks[r];
    size_t rowq = (size_t)(b * NTOK + tok) * 256 + h * 32;
    const uint4* q4 = reinterpret_cast<const uint4*>(qkv + rowq + cp * 8);
    const uint4* k4 = reinterpret_cast<const uint4*>(qkv + (size_t)BN * 256 + rowq + cp * 8);
    const uint4* v4 = reinterpret_cast<const uint4*>(qkv + (size_t)2 * BN * 256 + rowq + cp * 8);
    uint4 qa = q4[0], qb = q4[1];
    uint4 ka = k4[0], kb = k4[1];
    uint4 va = v4[0], vb = v4[1];
    *reinterpret_cast<uint4*>(&Qs[r * 32 + SW4(cp, r) * 8]) = qa;
    *reinterpret_cast<uint4*>(&Qs[r * 32 + SW4(cp + 1, r) * 8]) = qb;
    *reinterpret_cast<uint4*>(&Ks[r * 32 + SW4(cp, r) * 8]) = ka;
    *reinterpret_cast<uint4*>(&Ks[r * 32 + SW4(cp + 1, r) * 8]) = kb;
    int chunk_t = r >> 3, tl = r & 7;
    const ushort* pva = reinterpret_cast<const ushort*>(&va);
    const ushort* pvb = reinterpret_cast<const ushort*>(&vb);
#pragma unroll
    for (int e = 0; e < 8; ++e) {
      int ch = cp * 8 + e;
      Vt[ch * 128 + ((chunk_t ^ ((ch & 7) << 1)) << 3) + tl] = pva[e];
      int ch2 = ch + 8;
      Vt[ch2 * 128 + ((chunk_t ^ ((ch2 & 7) << 1)) << 3) + tl] = pvb[e];
    }
  }
  __syncthreads();

  // QK^T: each wave computes 32x128 of S
  f32x4 sacc[2][8] = {};
  {
    short8 aq[2], bk[8];
#pragma unroll
    for (int m = 0; m < 2; ++m) {
      int r = wave * 32 + m * 16 + l15;
      aq[m] = *reinterpret_cast<const short8*>(&Qs[r * 32 + SW4(hi, r) * 8]);
    }
#pragma unroll
    for (int n = 0; n < 8; ++n) {
      int r = n * 16 + l15;
      bk[n] = *reinterpret_cast<const short8*>(&Ks[r * 32 + SW4(hi, r) * 8]);
    }
#pragma unroll
    for (int m = 0; m < 2; ++m)
#pragma unroll
      for (int n = 0; n < 8; ++n)
        sacc[m][n] = __builtin_amdgcn_mfma_f32_16x16x32_bf16(aq[m], bk[n], sacc[m][n], 0, 0, 0);
  }
  __syncthreads();   // all Qs/Ks reads done before Ps overwrites them

  // softmax over rows (row = wave*32 + m*16 + hi*4 + j; cols across 16-lane group)
  const float cexp = 0.17677669529663687f * 1.4426950408889634f;  // scale*log2(e)
#pragma unroll
  for (int m = 0; m < 2; ++m) {
#pragma unroll
    for (int j = 0; j < 4; ++j) {
      float mx = -1e30f;
#pragma unroll
      for (int n = 0; n < 8; ++n) mx = fmaxf(mx, sacc[m][n][j]);
#pragma unroll
      for (int d = 1; d < 16; d <<= 1) mx = fmaxf(mx, __shfl_xor(mx, d));
      float pv[8], sum = 0.f;
#pragma unroll
      for (int n = 0; n < 8; ++n) { pv[n] = exp2f((sacc[m][n][j] - mx) * cexp); sum += pv[n]; }
#pragma unroll
      for (int d = 1; d < 16; d <<= 1) sum += __shfl_xor(sum, d);
      float inv = 1.0f / sum;
      int row = wave * 32 + m * 16 + hi * 4 + j;
#pragma unroll
      for (int n = 0; n < 8; ++n) {
        int col = n * 16 + l15;
        int chunk = col >> 3;
        Ps[row * 128 + ((chunk ^ (row & 7)) << 3) + (col & 7)] = f2bf(pv[n] * inv);
      }
    }
  }
  __syncthreads();

  // PV: out 32x32 per wave, K=128
  f32x4 oacc[2][2] = {};
#pragma unroll
  for (int kk = 0; kk < 4; ++kk) {
    int k0 = kk * 32 + hi * 8;
    int chunk = k0 >> 3;
    short8 pa[2], bv[2];
#pragma unroll
    for (int m = 0; m < 2; ++m) {
      int r = wave * 32 + m * 16 + l15;
      pa[m] = *reinterpret_cast<const short8*>(&Ps[r * 128 + ((chunk ^ (r & 7)) << 3)]);
    }
#pragma unroll
    for (int n = 0; n < 2; ++n) {
      int ch = n * 16 + l15;
      bv[n] = *reinterpret_cast<const short8*>(&Vt[ch * 128 + ((chunk ^ ((ch & 7) << 1)) << 3)]);
    }
#pragma unroll
    for (int m = 0; m < 2; ++m)
#pragma unroll
      for (int n = 0; n < 2; ++n)
        oacc[m][n] = __builtin_amdgcn_mfma_f32_16x16x32_bf16(pa[m], bv[n], oacc[m][n], 0, 0, 0);
  }

  // stage out-tile [128][32] into Ps region, then 2 threads/token write 64B
  __syncthreads();             // PV's Ps/Vt reads complete
  ushort* Ot = Ps;
#pragma unroll
  for (int m = 0; m < 2; ++m) {
    int rb = wave * 32 + m * 16 + hi * 4;
#pragma unroll
    for (int j = 0; j < 4; ++j)
#pragma unroll
      for (int n = 0; n < 2; ++n)
        Ot[(rb + j) * 32 + n * 16 + l15] = f2bf(oacc[m][n][j]);
  }
  __syncthreads();
  {
    int tr = tid >> 1, part = tid & 1;
    int tok = toks[tr];
    size_t base = ((size_t)(b * NTOK + tok)) * 256 + h * 32 + part * 16;
    const uint4* src = reinterpret_cast<const uint4*>(Ot + tr * 32 + part * 16);
    uint4 v0 = src[0], v1 = src[1];
    *reinterpret_cast<uint4*>(attn_out + base) = v0;
    *reinterpret_cast<uint4*>(attn_out + base + 8) = v1;
  }
}

// ---------------------------------------------------------------------------
// K4: output projection: attn(bf16) x Wp^T + bp -> f32 out.
// Same deep-prefetch structure as K2; swizzled f32 epilogue staging.
// ---------------------------------------------------------------------------
__global__ __launch_bounds__(512, 4) void k_proj_out(
    const ushort* __restrict__ Abf, const ushort* __restrict__ Wp_img,
    const float* __restrict__ bp, float* __restrict__ out) {
  __shared__ ushort As[128 * 64];
  __shared__ ushort Bs[2][256 * 64];
  int mt = blockIdx.x;
  int row0 = mt * 128;

  int tid = threadIdx.x, lane = tid & 63, wave = tid >> 6;
  int l15 = lane & 15, hi = lane >> 4;
  int wr = (wave >> 2) * 64, wc = (wave & 3) * 64;
  int sr = tid >> 2, sq = tid & 3;

  const ushort* aptr = Abf + (size_t)(row0 + sr) * 256 + sq * 16;
  int boff = wave * 4096 + lane * 16;

  f32x4 acc[4][4] = {};
  uint4 ar[4][2];
#pragma unroll
  for (int ks = 0; ks < 4; ++ks) {
    const uint4* p = reinterpret_cast<const uint4*>(aptr + ks * 64);
    ar[ks][0] = p[0]; ar[ks][1] = p[1];
  }
#pragma unroll
  for (int j = 0; j < 4; ++j)
    gl16((const char*)Wp_img + boff + j * 1024, (char*)Bs[0] + boff + j * 1024);

#pragma unroll
  for (int ks = 0; ks < 4; ++ks) {
    *reinterpret_cast<uint4*>(&As[sr * 64 + (((sq * 2) ^ (sr & 7)) << 3)]) = ar[ks][0];
    *reinterpret_cast<uint4*>(&As[sr * 64 + (((sq * 2 + 1) ^ (sr & 7)) << 3)]) = ar[ks][1];
    __syncthreads();
    if (ks < 3) {
#pragma unroll
      for (int j = 0; j < 4; ++j)
        gl16((const char*)Wp_img + (ks + 1) * 32768 + boff + j * 1024,
             (char*)Bs[(ks + 1) & 1] + boff + j * 1024);
    }
    const ushort* Bcur = Bs[ks & 1];
#pragma unroll
    for (int kk = 0; kk < 2; ++kk) {
      int ck = kk * 4 + hi;
      short8 af[4], bfr[4];
#pragma unroll
      for (int m = 0; m < 4; ++m) {
        int r = wr + m * 16 + l15;
        af[m] = *reinterpret_cast<const short8*>(&As[r * 64 + ((ck ^ (r & 7)) << 3)]);
      }
#pragma unroll
      for (int n = 0; n < 4; ++n) {
        int r = wc + n * 16 + l15;
        bfr[n] = *reinterpret_cast<const short8*>(&Bcur[r * 64 + ((ck ^ (r & 7)) << 3)]);
      }
#pragma unroll
      for (int m = 0; m < 4; ++m)
#pragma unroll
        for (int n = 0; n < 4; ++n)
          acc[m][n] = __builtin_amdgcn_mfma_f32_16x16x32_bf16(af[m], bfr[n], acc[m][n], 0, 0, 0);
    }
    __syncthreads();
  }

  // epilogue: two 64-row halves through Bs (64KB f32), chunk-swizzled staging,
  // fully coalesced float4 stores.
  float* Of = (float*)Bs;
#pragma unroll
  for (int hf = 0; hf < 2; ++hf) {
    if (hf) __syncthreads();          // previous half's sweep done
    if ((wave >> 2) == hf) {
#pragma unroll
      for (int n = 0; n < 4; ++n) {
        int col = wc + n * 16 + l15;
        float bv = bp[col];
        int c = col >> 2, ci = col & 3;
#pragma unroll
        for (int m = 0; m < 4; ++m) {
          int lr = m * 16 + hi * 4;   // local row within half
#pragma unroll
          for (int j = 0; j < 4; ++j) {
            int r = lr + j;
            int slot = c ^ (((r >> 2) & 3) << 2);
            Of[r * 256 + slot * 4 + ci] = acc[m][n][j] + bv;
          }
        }
      }
    }
    __syncthreads();
    size_t gbase = (size_t)(row0 + hf * 64) * 256;
#pragma unroll
    for (int s = 0; s < 8; ++s) {
      int off = s * 2048 + tid * 4;
      int r = off >> 8, cc = (off >> 2) & 63;
      int slot = cc ^ (((r >> 2) & 3) << 2);
      *reinterpret_cast<float4*>(out + gbase + off) =
          *reinterpret_cast<const float4*>(Of + r * 256 + slot * 4);
    }
  }
}

// ---------------------------------------------------------------------------
extern "C" void kernel_launch(void* const* d_in, const int* in_sizes, int n_in,
                              void* d_out, int out_size, void* d_ws, size_t ws_size,
                              hipStream_t stream) {
  const float* xq = (const float*)d_in[0];
  const float* xk = (const float*)d_in[1];
  const float* xv = (const float*)d_in[2];
  const float* Wq = (const float*)d_in[3];
  const float* bq = (const float*)d_in[4];
  const float* Wp = (const float*)d_in[5];
  const float* bp = (const float*)d_in[6];
  const int*   vor = (const int*)d_in[7];

  char* ws = (char*)d_ws;
  // layout: qkv bf16 [3][BN][256] | attn bf16 [BN][256] | grp | cnt | Wq_img | Wp_img
  ushort* qkv    = (ushort*)ws;                                 // 201,326,592 B
  ushort* attn   = (ushort*)(ws + (size_t)201326592);           //  67,108,864 B
  int*    grp    = (int*)(ws + (size_t)268435456);              //     524,288 B
  int*    cnt    = (int*)(ws + (size_t)268959744);              //       4,096 B
  ushort* Wq_img = (ushort*)(ws + (size_t)268963840);           //     131,072 B
  ushort* Wp_img = (ushort*)(ws + (size_t)269094912);           //     131,072 B

  hipMemsetAsync(cnt, 0, B_ * G_ * sizeof(int), stream);
  k_prep<<<dim3(64), dim3(256), 0, stream>>>(Wq, Wp, Wq_img, Wp_img);
  k_group<<<dim3(BN / 256), dim3(256), 0, stream>>>(vor, grp, cnt);
  k_proj_qkv<<<dim3(M3 / 128), dim3(512), 0, stream>>>(xq, xk, xv, Wq_img, bq, qkv);
  k_attn<<<dim3(B_ * G_ * H_), dim3(256), 0, stream>>>(qkv, grp, attn);
  k_proj_out<<<dim3(BN / 128), dim3(512), 0, stream>>>(attn, Wp_img, bp, (float*)d_out);
}

// Round 6
// 318.113 us; speedup vs baseline: 1.3051x; 1.3051x over previous
//
#include <hip/hip_runtime.h>
#include <hip/hip_bf16.h>

// Problem constants (hardcoded from setup_inputs)
#define B_    2
#define NTOK  65536          // tokens per batch (256*256)
#define C_    256
#define H_    8
#define HD_   32
#define G_    512
#define S_    128            // tokens per cell
#define BN    (B_*NTOK)      // 131072 rows per tensor
#define M3    (3*BN)         // 393216 rows for fused qkv GEMM

typedef __attribute__((ext_vector_type(8))) short short8;   // 8 bf16 = 4 VGPRs
typedef __attribute__((ext_vector_type(4))) float f32x4;

// Native bf16 convert (RNE) — lowers to v_cvt_pk_bf16_f32 on gfx950.
__device__ __forceinline__ ushort f2bf(float f) {
  __bf16 h = (__bf16)f;
  return __builtin_bit_cast(unsigned short, h);
}
__device__ __forceinline__ unsigned pk2(float lo, float hi) {
  return (unsigned)f2bf(lo) | ((unsigned)f2bf(hi) << 16);
}

// async global->LDS, 16B per lane, wave-uniform LDS base + lane*16
__device__ __forceinline__ void gl16(const void* g, void* l) {
  __builtin_amdgcn_global_load_lds(
      (const __attribute__((address_space(1))) unsigned int*)g,
      (__attribute__((address_space(3))) unsigned int*)l, 16, 0, 0);
}

// swizzle for 4-chunk rows (32 bf16/row): slot = (c ^ r ^ (r>>2)) & 3
#define SW4(c, r) ((((c) ^ (r) ^ ((r) >> 2))) & 3)

// ---------------------------------------------------------------------------
// K0: build pre-swizzled bf16 LDS tile images of Wq and Wp.
// ---------------------------------------------------------------------------
__global__ __launch_bounds__(256) void k_prep(const float* __restrict__ Wq,
                                              const float* __restrict__ Wp,
                                              ushort* __restrict__ Wq_img,
                                              ushort* __restrict__ Wp_img) {
  int gid = blockIdx.x * 256 + threadIdx.x;     // [2][4][256][8] = 16384 tasks
  int w = gid >> 13, rem = gid & 8191;
  int ks = rem >> 11, rem2 = rem & 2047;
  int r = rem2 >> 3, c = rem2 & 7;
  const float* W = w ? Wp : Wq;
  ushort* img = w ? Wp_img : Wq_img;
  const float4* s = reinterpret_cast<const float4*>(W + (size_t)r * 256 + ks * 64 + c * 8);
  float4 a = s[0], b = s[1];
  uint4 o;
  o.x = pk2(a.x, a.y); o.y = pk2(a.z, a.w);
  o.z = pk2(b.x, b.y); o.w = pk2(b.z, b.w);
  *reinterpret_cast<uint4*>(img + ks * 16384 + r * 64 + ((c ^ (r & 7)) << 3)) = o;
}

// ---------------------------------------------------------------------------
// K1: build per-(batch,cell) token lists via atomics.
// ---------------------------------------------------------------------------
__global__ __launch_bounds__(256) void k_group(const int* __restrict__ vor,
                                               int* __restrict__ grp,
                                               int* __restrict__ cnt) {
  int idx = blockIdx.x * 256 + threadIdx.x;
  int b = idx >> 16;
  int n = idx & (NTOK - 1);
  int g = vor[idx] - 1;
  int pos = atomicAdd(&cnt[(b << 9) + g], 1);
  grp[((b << 9) + g) * S_ + pos] = n;
}

// ---------------------------------------------------------------------------
// K2: fused QKV projection: [M3,256] x Wq^T + bq -> bf16 qkv[3][BN][256]
// 128x256 tile, BK=64, 8 waves. Counted-vmcnt pipeline: raw barriers, B
// gl16s and next-step A loads stay in flight across barriers (never vmcnt(0)
// in the loop body until the final step). Swizzled coalesced epilogue.
// ---------------------------------------------------------------------------
__global__ __launch_bounds__(512, 4) void k_proj_qkv(
    const float* __restrict__ xq, const float* __restrict__ xk,
    const float* __restrict__ xv, const ushort* __restrict__ Wq_img,
    const float* __restrict__ bq, ushort* __restrict__ qkv) {
  __shared__ ushort As[128 * 64];
  __shared__ ushort Bs[2][256 * 64];
  int mt = blockIdx.x;
  int t = mt >> 10;                             // which of xq/xk/xv
  const float* A = (t == 0) ? xq : (t == 1) ? xk : xv;
  size_t abase = (size_t)(mt & 1023) * 128 * 256;
  int row0 = mt * 128;

  int tid = threadIdx.x, lane = tid & 63, wave = tid >> 6;
  int l15 = lane & 15, hi = lane >> 4;
  int wr = (wave >> 2) * 64, wc = (wave & 3) * 64;
  int sr = tid >> 2, sq = tid & 3;              // A staging: row, quarter

  const float* aptr = A + abase + (size_t)sr * 256 + sq * 16;
  int boff = wave * 4096 + lane * 16;           // B staging byte offset

  f32x4 acc[4][4] = {};
  float4 ar[2][4];                              // 2-deep alternating prefetch
  {
    const float4* p = reinterpret_cast<const float4*>(aptr);
#pragma unroll
    for (int j = 0; j < 4; ++j) ar[0][j] = p[j];
  }
#pragma unroll
  for (int j = 0; j < 4; ++j)
    gl16((const char*)Wq_img + boff + j * 1024, (char*)Bs[0] + boff + j * 1024);

#pragma unroll
  for (int ks = 0; ks < 4; ++ks) {
    // P1: stage A[ks] (compiler auto-waits on ar[ks&1]'s loads)
    uint4 w0, w1;
    w0.x = pk2(ar[ks & 1][0].x, ar[ks & 1][0].y); w0.y = pk2(ar[ks & 1][0].z, ar[ks & 1][0].w);
    w0.z = pk2(ar[ks & 1][1].x, ar[ks & 1][1].y); w0.w = pk2(ar[ks & 1][1].z, ar[ks & 1][1].w);
    w1.x = pk2(ar[ks & 1][2].x, ar[ks & 1][2].y); w1.y = pk2(ar[ks & 1][2].z, ar[ks & 1][2].w);
    w1.z = pk2(ar[ks & 1][3].x, ar[ks & 1][3].y); w1.w = pk2(ar[ks & 1][3].z, ar[ks & 1][3].w);
    *reinterpret_cast<uint4*>(&As[sr * 64 + (((sq * 2) ^ (sr & 7)) << 3)]) = w0;
    *reinterpret_cast<uint4*>(&As[sr * 64 + (((sq * 2 + 1) ^ (sr & 7)) << 3)]) = w1;
    // P2/P3: issue next-step A loads + B gl16 (stay in flight across barriers)
    if (ks < 3) {
      const float4* p = reinterpret_cast<const float4*>(aptr + (ks + 1) * 64);
#pragma unroll
      for (int j = 0; j < 4; ++j) ar[(ks + 1) & 1][j] = p[j];
#pragma unroll
      for (int j = 0; j < 4; ++j)
        gl16((const char*)Wq_img + (ks + 1) * 32768 + boff + j * 1024,
             (char*)Bs[(ks + 1) & 1] + boff + j * 1024);
      asm volatile("s_waitcnt vmcnt(8)" ::: "memory");   // B[ks] gl16s done
    } else {
      asm volatile("s_waitcnt vmcnt(0)" ::: "memory");   // final drain
    }
    asm volatile("s_waitcnt lgkmcnt(0)" ::: "memory");   // own ds_writes visible
    __builtin_amdgcn_s_barrier();
    // P7: MFMA phase
    const ushort* Bcur = Bs[ks & 1];
#pragma unroll
    for (int kk = 0; kk < 2; ++kk) {
      int ck = kk * 4 + hi;
      short8 af[4], bfr[4];
#pragma unroll
      for (int m = 0; m < 4; ++m) {
        int r = wr + m * 16 + l15;
        af[m] = *reinterpret_cast<const short8*>(&As[r * 64 + ((ck ^ (r & 7)) << 3)]);
      }
#pragma unroll
      for (int n = 0; n < 4; ++n) {
        int r = wc + n * 16 + l15;
        bfr[n] = *reinterpret_cast<const short8*>(&Bcur[r * 64 + ((ck ^ (r & 7)) << 3)]);
      }
#pragma unroll
      for (int m = 0; m < 4; ++m)
#pragma unroll
        for (int n = 0; n < 4; ++n)
          acc[m][n] = __builtin_amdgcn_mfma_f32_16x16x32_bf16(af[m], bfr[n], acc[m][n], 0, 0, 0);
    }
    // P8: all LDS reads done before next step overwrites
    asm volatile("s_waitcnt lgkmcnt(0)" ::: "memory");
    __builtin_amdgcn_s_barrier();
  }

  // epilogue: swizzled LDS staging -> coalesced 16B stores (0 bank conflicts)
  ushort* Ot = (ushort*)Bs;                     // 64KB = 128 rows x 32 chunks
#pragma unroll
  for (int n = 0; n < 4; ++n) {
    int col = wc + n * 16 + l15;
    float bv = bq[col];
    int c = col >> 3, ci = col & 7;
#pragma unroll
    for (int m = 0; m < 4; ++m) {
      int r0 = wr + m * 16 + hi * 4;
#pragma unroll
      for (int j = 0; j < 4; ++j) {
        int r = r0 + j;
        int slot = c ^ (((r >> 2) & 3) << 1);
        Ot[r * 256 + slot * 8 + ci] = f2bf(acc[m][n][j] + bv);
      }
    }
  }
  __syncthreads();
  {
    size_t gbase = (size_t)row0 * 256;
#pragma unroll
    for (int s = 0; s < 8; ++s) {
      int off = s * 4096 + tid * 8;
      int r = off >> 8, cc = (off >> 3) & 31;
      int slot = cc ^ (((r >> 2) & 3) << 1);
      *reinterpret_cast<uint4*>(qkv + gbase + off) =
          *reinterpret_cast<const uint4*>(Ot + r * 256 + slot * 8);
    }
  }
}

// ---------------------------------------------------------------------------
// K3: per-(b,cell,head) attention (unchanged from round 4).
// ---------------------------------------------------------------------------
__global__ __launch_bounds__(256) void k_attn(const ushort* __restrict__ qkv,
                                              const int* __restrict__ grp,
                                              ushort* __restrict__ attn_out) {
  __shared__ int toks[128];
  __shared__ ushort PsB[128 * 128];   // phase1: Qs=[0,4096) Ks=[4096,8192); phase2: Ps
  __shared__ ushort Vt[32 * 128];     // V transposed: [ch][tok]
  ushort* Qs = PsB;
  ushort* Ks = PsB + 4096;
  ushort* Ps = PsB;

  int bid = blockIdx.x;
  int h = bid & 7, g = (bid >> 3) & (G_ - 1), b = bid >> 12;
  int tid = threadIdx.x, lane = tid & 63, wave = tid >> 6;
  int l15 = lane & 15, hi = lane >> 4;

  if (tid < 128) toks[tid] = grp[((b << 9) + g) * S_ + tid];
  __syncthreads();

  {  // stage Q,K (row-major, swizzled) and V (transposed, swizzled)
    int r = tid >> 1;
    int cp = (tid & 1) * 2;   // this thread covers chunks cp, cp+1
    int tok = toks[r];
    size_t rowq = (size_t)(b * NTOK + tok) * 256 + h * 32;
    const uint4* q4 = reinterpret_cast<const uint4*>(qkv + rowq + cp * 8);
    const uint4* k4 = reinterpret_cast<const uint4*>(qkv + (size_t)BN * 256 + rowq + cp * 8);
    const uint4* v4 = reinterpret_cast<const uint4*>(qkv + (size_t)2 * BN * 256 + rowq + cp * 8);
    uint4 qa = q4[0], qb = q4[1];
    uint4 ka = k4[0], kb = k4[1];
    uint4 va = v4[0], vb = v4[1];
    *reinterpret_cast<uint4*>(&Qs[r * 32 + SW4(cp, r) * 8]) = qa;
    *reinterpret_cast<uint4*>(&Qs[r * 32 + SW4(cp + 1, r) * 8]) = qb;
    *reinterpret_cast<uint4*>(&Ks[r * 32 + SW4(cp, r) * 8]) = ka;
    *reinterpret_cast<uint4*>(&Ks[r * 32 + SW4(cp + 1, r) * 8]) = kb;
    int chunk_t = r >> 3, tl = r & 7;
    const ushort* pva = reinterpret_cast<const ushort*>(&va);
    const ushort* pvb = reinterpret_cast<const ushort*>(&vb);
#pragma unroll
    for (int e = 0; e < 8; ++e) {
      int ch = cp * 8 + e;
      Vt[ch * 128 + ((chunk_t ^ ((ch & 7) << 1)) << 3) + tl] = pva[e];
      int ch2 = ch + 8;
      Vt[ch2 * 128 + ((chunk_t ^ ((ch2 & 7) << 1)) << 3) + tl] = pvb[e];
    }
  }
  __syncthreads();

  // QK^T: each wave computes 32x128 of S
  f32x4 sacc[2][8] = {};
  {
    short8 aq[2], bk[8];
#pragma unroll
    for (int m = 0; m < 2; ++m) {
      int r = wave * 32 + m * 16 + l15;
      aq[m] = *reinterpret_cast<const short8*>(&Qs[r * 32 + SW4(hi, r) * 8]);
    }
#pragma unroll
    for (int n = 0; n < 8; ++n) {
      int r = n * 16 + l15;
      bk[n] = *reinterpret_cast<const short8*>(&Ks[r * 32 + SW4(hi, r) * 8]);
    }
#pragma unroll
    for (int m = 0; m < 2; ++m)
#pragma unroll
      for (int n = 0; n < 8; ++n)
        sacc[m][n] = __builtin_amdgcn_mfma_f32_16x16x32_bf16(aq[m], bk[n], sacc[m][n], 0, 0, 0);
  }
  __syncthreads();   // all Qs/Ks reads done before Ps overwrites them

  // softmax over rows
  const float cexp = 0.17677669529663687f * 1.4426950408889634f;  // scale*log2(e)
#pragma unroll
  for (int m = 0; m < 2; ++m) {
#pragma unroll
    for (int j = 0; j < 4; ++j) {
      float mx = -1e30f;
#pragma unroll
      for (int n = 0; n < 8; ++n) mx = fmaxf(mx, sacc[m][n][j]);
#pragma unroll
      for (int d = 1; d < 16; d <<= 1) mx = fmaxf(mx, __shfl_xor(mx, d));
      float pv[8], sum = 0.f;
#pragma unroll
      for (int n = 0; n < 8; ++n) { pv[n] = exp2f((sacc[m][n][j] - mx) * cexp); sum += pv[n]; }
#pragma unroll
      for (int d = 1; d < 16; d <<= 1) sum += __shfl_xor(sum, d);
      float inv = 1.0f / sum;
      int row = wave * 32 + m * 16 + hi * 4 + j;
#pragma unroll
      for (int n = 0; n < 8; ++n) {
        int col = n * 16 + l15;
        int chunk = col >> 3;
        Ps[row * 128 + ((chunk ^ (row & 7)) << 3) + (col & 7)] = f2bf(pv[n] * inv);
      }
    }
  }
  __syncthreads();

  // PV: out 32x32 per wave, K=128
  f32x4 oacc[2][2] = {};
#pragma unroll
  for (int kk = 0; kk < 4; ++kk) {
    int k0 = kk * 32 + hi * 8;
    int chunk = k0 >> 3;
    short8 pa[2], bv[2];
#pragma unroll
    for (int m = 0; m < 2; ++m) {
      int r = wave * 32 + m * 16 + l15;
      pa[m] = *reinterpret_cast<const short8*>(&Ps[r * 128 + ((chunk ^ (r & 7)) << 3)]);
    }
#pragma unroll
    for (int n = 0; n < 2; ++n) {
      int ch = n * 16 + l15;
      bv[n] = *reinterpret_cast<const short8*>(&Vt[ch * 128 + ((chunk ^ ((ch & 7) << 1)) << 3)]);
    }
#pragma unroll
    for (int m = 0; m < 2; ++m)
#pragma unroll
      for (int n = 0; n < 2; ++n)
        oacc[m][n] = __builtin_amdgcn_mfma_f32_16x16x32_bf16(pa[m], bv[n], oacc[m][n], 0, 0, 0);
  }

  // stage out-tile [128][32] into Ps region, then 2 threads/token write 64B
  __syncthreads();             // PV's Ps/Vt reads complete
  ushort* Ot = Ps;
#pragma unroll
  for (int m = 0; m < 2; ++m) {
    int rb = wave * 32 + m * 16 + hi * 4;
#pragma unroll
    for (int j = 0; j < 4; ++j)
#pragma unroll
      for (int n = 0; n < 2; ++n)
        Ot[(rb + j) * 32 + n * 16 + l15] = f2bf(oacc[m][n][j]);
  }
  __syncthreads();
  {
    int tr = tid >> 1, part = tid & 1;
    int tok = toks[tr];
    size_t base = ((size_t)(b * NTOK + tok)) * 256 + h * 32 + part * 16;
    const uint4* src = reinterpret_cast<const uint4*>(Ot + tr * 32 + part * 16);
    uint4 v0 = src[0], v1 = src[1];
    *reinterpret_cast<uint4*>(attn_out + base) = v0;
    *reinterpret_cast<uint4*>(attn_out + base + 8) = v1;
  }
}

// ---------------------------------------------------------------------------
// K4: output projection: attn(bf16) x Wp^T + bp -> f32 out.
// Same counted-vmcnt pipeline; swizzled f32 epilogue staging.
// ---------------------------------------------------------------------------
__global__ __launch_bounds__(512, 4) void k_proj_out(
    const ushort* __restrict__ Abf, const ushort* __restrict__ Wp_img,
    const float* __restrict__ bp, float* __restrict__ out) {
  __shared__ ushort As[128 * 64];
  __shared__ ushort Bs[2][256 * 64];
  int mt = blockIdx.x;
  int row0 = mt * 128;

  int tid = threadIdx.x, lane = tid & 63, wave = tid >> 6;
  int l15 = lane & 15, hi = lane >> 4;
  int wr = (wave >> 2) * 64, wc = (wave & 3) * 64;
  int sr = tid >> 2, sq = tid & 3;

  const ushort* aptr = Abf + (size_t)(row0 + sr) * 256 + sq * 16;
  int boff = wave * 4096 + lane * 16;

  f32x4 acc[4][4] = {};
  uint4 ar[2][2];
  {
    const uint4* p = reinterpret_cast<const uint4*>(aptr);
    ar[0][0] = p[0]; ar[0][1] = p[1];
  }
#pragma unroll
  for (int j = 0; j < 4; ++j)
    gl16((const char*)Wp_img + boff + j * 1024, (char*)Bs[0] + boff + j * 1024);

#pragma unroll
  for (int ks = 0; ks < 4; ++ks) {
    *reinterpret_cast<uint4*>(&As[sr * 64 + (((sq * 2) ^ (sr & 7)) << 3)]) = ar[ks & 1][0];
    *reinterpret_cast<uint4*>(&As[sr * 64 + (((sq * 2 + 1) ^ (sr & 7)) << 3)]) = ar[ks & 1][1];
    if (ks < 3) {
      const uint4* p = reinterpret_cast<const uint4*>(aptr + (ks + 1) * 64);
      ar[(ks + 1) & 1][0] = p[0]; ar[(ks + 1) & 1][1] = p[1];
#pragma unroll
      for (int j = 0; j < 4; ++j)
        gl16((const char*)Wp_img + (ks + 1) * 32768 + boff + j * 1024,
             (char*)Bs[(ks + 1) & 1] + boff + j * 1024);
      asm volatile("s_waitcnt vmcnt(6)" ::: "memory");   // B[ks] gl16s done
    } else {
      asm volatile("s_waitcnt vmcnt(0)" ::: "memory");
    }
    asm volatile("s_waitcnt lgkmcnt(0)" ::: "memory");
    __builtin_amdgcn_s_barrier();
    const ushort* Bcur = Bs[ks & 1];
#pragma unroll
    for (int kk = 0; kk < 2; ++kk) {
      int ck = kk * 4 + hi;
      short8 af[4], bfr[4];
#pragma unroll
      for (int m = 0; m < 4; ++m) {
        int r = wr + m * 16 + l15;
        af[m] = *reinterpret_cast<const short8*>(&As[r * 64 + ((ck ^ (r & 7)) << 3)]);
      }
#pragma unroll
      for (int n = 0; n < 4; ++n) {
        int r = wc + n * 16 + l15;
        bfr[n] = *reinterpret_cast<const short8*>(&Bcur[r * 64 + ((ck ^ (r & 7)) << 3)]);
      }
#pragma unroll
      for (int m = 0; m < 4; ++m)
#pragma unroll
        for (int n = 0; n < 4; ++n)
          acc[m][n] = __builtin_amdgcn_mfma_f32_16x16x32_bf16(af[m], bfr[n], acc[m][n], 0, 0, 0);
    }
    asm volatile("s_waitcnt lgkmcnt(0)" ::: "memory");
    __builtin_amdgcn_s_barrier();
  }

  // epilogue: two 64-row halves through Bs (64KB f32), chunk-swizzled staging,
  // fully coalesced float4 stores.
  float* Of = (float*)Bs;
#pragma unroll
  for (int hf = 0; hf < 2; ++hf) {
    if (hf) __syncthreads();          // previous half's sweep done
    if ((wave >> 2) == hf) {
#pragma unroll
      for (int n = 0; n < 4; ++n) {
        int col = wc + n * 16 + l15;
        float bv = bp[col];
        int c = col >> 2, ci = col & 3;
#pragma unroll
        for (int m = 0; m < 4; ++m) {
          int lr = m * 16 + hi * 4;   // local row within half
#pragma unroll
          for (int j = 0; j < 4; ++j) {
            int r = lr + j;
            int slot = c ^ (((r >> 2) & 3) << 2);
            Of[r * 256 + slot * 4 + ci] = acc[m][n][j] + bv;
          }
        }
      }
    }
    __syncthreads();
    size_t gbase = (size_t)(row0 + hf * 64) * 256;
#pragma unroll
    for (int s = 0; s < 8; ++s) {
      int off = s * 2048 + tid * 4;
      int r = off >> 8, cc = (off >> 2) & 63;
      int slot = cc ^ (((r >> 2) & 3) << 2);
      *reinterpret_cast<float4*>(out + gbase + off) =
          *reinterpret_cast<const float4*>(Of + r * 256 + slot * 4);
    }
  }
}

// ---------------------------------------------------------------------------
extern "C" void kernel_launch(void* const* d_in, const int* in_sizes, int n_in,
                              void* d_out, int out_size, void* d_ws, size_t ws_size,
                              hipStream_t stream) {
  const float* xq = (const float*)d_in[0];
  const float* xk = (const float*)d_in[1];
  const float* xv = (const float*)d_in[2];
  const float* Wq = (const float*)d_in[3];
  const float* bq = (const float*)d_in[4];
  const float* Wp = (const float*)d_in[5];
  const float* bp = (const float*)d_in[6];
  const int*   vor = (const int*)d_in[7];

  char* ws = (char*)d_ws;
  // layout: qkv bf16 [3][BN][256] | attn bf16 [BN][256] | grp | cnt | Wq_img | Wp_img
  ushort* qkv    = (ushort*)ws;                                 // 201,326,592 B
  ushort* attn   = (ushort*)(ws + (size_t)201326592);           //  67,108,864 B
  int*    grp    = (int*)(ws + (size_t)268435456);              //     524,288 B
  int*    cnt    = (int*)(ws + (size_t)268959744);              //       4,096 B
  ushort* Wq_img = (ushort*)(ws + (size_t)268963840);           //     131,072 B
  ushort* Wp_img = (ushort*)(ws + (size_t)269094912);           //     131,072 B

  hipMemsetAsync(cnt, 0, B_ * G_ * sizeof(int), stream);
  k_prep<<<dim3(64), dim3(256), 0, stream>>>(Wq, Wp, Wq_img, Wp_img);
  k_group<<<dim3(BN / 256), dim3(256), 0, stream>>>(vor, grp, cnt);
  k_proj_qkv<<<dim3(M3 / 128), dim3(512), 0, stream>>>(xq, xk, xv, Wq_img, bq, qkv);
  k_attn<<<dim3(B_ * G_ * H_), dim3(256), 0, stream>>>(qkv, grp, attn);
  k_proj_out<<<dim3(BN / 128), dim3(512), 0, stream>>>(attn, Wp_img, bp, (float*)d_out);
}